// Round 11
// baseline (579.337 us; speedup 1.0000x reference)
//
#include <hip/hip_runtime.h>
#include <hip/hip_bf16.h>

// GCN_5016521802361: 2x SAGEConv(aggr='lstm', project=True), N=50000, D=16, F=128, C=40.
// Round 24: inline x-conversion. x (12.8MB, 80% of converted bytes) is consumed
// only as MFMA A-fragments in the two stage-A GEMMs -> convert at fragment-load
// time (uniform branch on dtype flag; f32 path = 2x float4 + 8 RNE cvts,
// identical rounding -> bit-identical). convert_inputs now touches only ~1.3MB
// of weights (grid 1024->128). Producers r23-exact otherwise ((256,3), kt/ct
// half splits); lstm kernels r22/r23-exact (plateau core + EPI=1 final linear).

typedef __hip_bfloat16 bf16;
typedef __attribute__((ext_vector_type(8))) short short8;
typedef __attribute__((ext_vector_type(4))) short short4v;
typedef __attribute__((ext_vector_type(4))) float floatx4;
typedef __attribute__((ext_vector_type(4))) float float4v;

#define LOG2E 1.4426950408889634f
#define TWOL  2.8853900817779268f

__device__ __forceinline__ float bf2f(bf16 v) { return __bfloat162float(v); }
__device__ __forceinline__ bf16  f2bf(float v) { return __float2bfloat16(v); }
__device__ __forceinline__ float bfs2f(short s) {
    union { float f; unsigned u; } v; v.u = ((unsigned)(unsigned short)s) << 16; return v.f;
}
__device__ __forceinline__ short f2bfs(float v) {
    bf16 b = __float2bfloat16(v); return *(short*)&b;
}

__device__ __forceinline__ float ex2(float x) {
#if __has_builtin(__builtin_amdgcn_exp2f)
    return __builtin_amdgcn_exp2f(x);
#else
    return exp2f(x);
#endif
}

// LSTM cell, prescaled inputs: i_,f_,o_ carry log2e, g_ carries 2*log2e,
// c is tracked as (2*log2e)*c_true. Single merged rcp on the c path.
__device__ __forceinline__ float cell(float i_, float f_, float g_, float o_, float& c) {
    float ei = ex2(-i_), ef = ex2(-f_), eg = ex2(g_), eo = ex2(-o_);
    float A = (1.f + ei) * (eg + 1.f);
    float B = 1.f + ef;
    float cn = fmaf(c, A, fmaf(eg, TWOL, -TWOL) * B) * __builtin_amdgcn_rcpf(A * B);
    c = cn;
    float ec = ex2(cn);
    return (ec - 1.f) * __builtin_amdgcn_rcpf((ec + 1.f) * (1.f + eo));
}

// Permuted-Y memory position p -> source gate row. Convert-time only.
__device__ __forceinline__ int ydecode(int p) {
    int pw = (p >> 6) & 7, pq = (p >> 4) & 3, pg = (p >> 2) & 3, pr = p & 3;
    return pg * 128 + pw * 16 + pq * 4 + pr;
}

// load 8 bf16 of row `row` at element offset `off` from raw x (f32 or bf16);
// f32 path converts with RNE -> bit-identical to the old convert kernel.
__device__ __forceinline__ short8 load_x8(const void* X, bool isf32, size_t row, int off) {
    if (isf32) {
        const float* p = (const float*)X + row * 128 + off;
        float4v a = *(const float4v*)p, b = *(const float4v*)(p + 4);
        short8 r;
#pragma unroll
        for (int j = 0; j < 4; j++) { r[j] = f2bfs(a[j]); r[4 + j] = f2bfs(b[j]); }
        return r;
    }
    return *(const short8*)((const bf16*)X + row * 128 + off);
}

__device__ __forceinline__ void dma1(const bf16* gp, void* lp) {
    __builtin_amdgcn_global_load_lds(
        (const __attribute__((address_space(1))) void*)gp,
        (__attribute__((address_space(3))) void*)lp, 16, 0, 0);
}

__device__ __forceinline__ void dma2(const bf16* gp, void* lp0, void* lp1) {
    dma1(gp, lp0);
    dma1(gp + 32, lp1);
}

// mode 0: plain copy; mode 1: Whh gate-scale; mode 2: Wih permute+scale;
// mode 3: bias pair sum -> f32 dst (permuted+scaled)
struct Cvt { const void* src; const void* src2; bf16* dst; int n; int mode; };
struct CvtAll { Cvt t[16]; };

__global__ void convert_inputs(CvtAll ca, const unsigned short* __restrict__ xb,
                               int* __restrict__ flag) {
    __shared__ int sflag;
    {
        int cnt = 0;
        for (int i = threadIdx.x; i < 1024; i += blockDim.x) {
            int e = (xb[i] >> 7) & 0xFF;
            cnt += (e >= 0xC8);
        }
        if (threadIdx.x == 0) sflag = 0;
        __syncthreads();
        if (cnt) atomicAdd(&sflag, cnt);
        __syncthreads();
    }
    const bool isf32 = (sflag >= 16);
    if (blockIdx.x == 0 && threadIdx.x == 0) *flag = isf32 ? 1 : 0;

    const int stride = gridDim.x * blockDim.x;
    const int tid0 = blockIdx.x * blockDim.x + threadIdx.x;
#pragma unroll 1
    for (int k = 0; k < 16; k++) {
        const int n = ca.t[k].n, mode = ca.t[k].mode;
        if (mode == 3) {
            const float* a32 = (const float*)ca.t[k].src;
            const float* b32 = (const float*)ca.t[k].src2;
            const short* a16 = (const short*)ca.t[k].src;
            const short* b16 = (const short*)ca.t[k].src2;
            float* df = (float*)ca.t[k].dst;
            for (int i = tid0; i < n; i += stride) {
                int yd = ydecode(i);
                float va = isf32 ? a32[yd] : bfs2f(a16[yd]);
                float vb = isf32 ? b32[yd] : bfs2f(b16[yd]);
                float m = ((((unsigned)i >> 2) & 3) == 2) ? TWOL : LOG2E;
                df[i] = (va + vb) * m;
            }
            continue;
        }
        const int n8 = n >> 3;
        bf16* d = ca.t[k].dst;
        for (int i = tid0; i < n8; i += stride) {
            int si = i;
            float m = 1.f;
            bool scaled = false;
            if (mode == 1) {
                m = ((((unsigned)i >> 11) & 3) == 2) ? TWOL : LOG2E; scaled = true;
            } else if (mode == 2) {
                int row = i >> 4;
                si = ydecode(row) * 16 + (i & 15);
                m = ((((unsigned)row >> 2) & 3) == 2) ? TWOL : LOG2E; scaled = true;
            }
            short8 ov;
            if (isf32) {
                const float4v* sp = (const float4v*)ca.t[k].src;
                float4v a = sp[2 * si], b = sp[2 * si + 1];
#pragma unroll
                for (int j = 0; j < 4; j++) {
                    ov[j]     = f2bfs(a[j] * m);
                    ov[4 + j] = f2bfs(b[j] * m);
                }
            } else {
                short8 sv = ((const short8*)ca.t[k].src)[si];
                if (scaled) {
#pragma unroll
                    for (int j = 0; j < 8; j++) ov[j] = f2bfs(bfs2f(sv[j]) * m);
                } else ov = sv;
            }
            ((short8*)d)[i] = ov;
        }
        if (mode == 0)
            for (int i = (n8 << 3) + tid0; i < n; i += stride) {
                float v = isf32 ? ((const float*)ca.t[k].src)[i]
                                : bfs2f(((const short*)ca.t[k].src)[i]);
                d[i] = f2bf(v);
            }
    }
}

// ---------------------------------------------------------------------------
// Fused layer entry: Y = (relu(X@Wp^T+bp)) @ Wihp^T(+bsum), permuted layout.
// X read RAW (f32 or bf16, uniform flag branch, inline RNE cvt).
// Stage A: kt-half split. Stage B: ct-half split, weights once, 4 rowtiles.
// ---------------------------------------------------------------------------
__global__ __launch_bounds__(256, 3) void fused_xp_y(
    const void* __restrict__ Xraw, const int* __restrict__ flag,
    const bf16* __restrict__ Wp, const bf16* __restrict__ bp,
    const bf16* __restrict__ Wihp, const float* __restrict__ bsum,
    bf16* __restrict__ Yout, int N)
{
    __shared__ bf16 T[64][136];
    const int tid = threadIdx.x;
    const int w = tid >> 6, l = tid & 63, q = l >> 4, lid = l & 15;
    const int rowbase = blockIdx.x * 64;
    const bool isf32 = (*flag != 0);

    int arow = rowbase + w * 16 + lid;
    if (arow >= N) arow = N - 1;

    // ---- stage A: xp = relu(X@Wp^T + bp) -> T (cols lid*8+ct), kt halves ----
    {
        floatx4 acc[8];
        float bvv[8];
#pragma unroll
        for (int ct = 0; ct < 8; ct++) {
            acc[ct] = (floatx4)(0.f);
            bvv[ct] = bf2f(bp[lid * 8 + ct]);
        }
#pragma unroll
        for (int kh = 0; kh < 2; kh++) {
            short8 bfrag[8][2];
#pragma unroll
            for (int ct = 0; ct < 8; ct++)
#pragma unroll
                for (int k2 = 0; k2 < 2; k2++)
                    bfrag[ct][k2] = *(const short8*)(Wp + (size_t)(lid * 8 + ct) * 128 + (kh * 2 + k2) * 32 + q * 8);
#pragma unroll
            for (int k2 = 0; k2 < 2; k2++) {
                short8 af = load_x8(Xraw, isf32, (size_t)arow, (kh * 2 + k2) * 32 + q * 8);
#pragma unroll
                for (int ct = 0; ct < 8; ct++)
                    acc[ct] = __builtin_amdgcn_mfma_f32_16x16x32_bf16(af, bfrag[ct][k2], acc[ct], 0, 0, 0);
            }
        }
#pragma unroll
        for (int r = 0; r < 4; r++) {
            short8 ov;
#pragma unroll
            for (int ct = 0; ct < 8; ct++)
                ov[ct] = f2bfs(fmaxf(acc[ct][r] + bvv[ct], 0.f));
            *(short8*)&T[w * 16 + q * 4 + r][lid * 8] = ov;
        }
    }
    __syncthreads();

    // ---- stage B: wave w = col chunk w; ct halves; 4 rowtiles each ----
#pragma unroll 1
    for (int hf = 0; hf < 2; hf++) {
        short8 wfr[4][4];
        float bv2[4];
#pragma unroll
        for (int ct = 0; ct < 4; ct++) {
            int pos = w * 128 + lid * 8 + hf * 4 + ct;
            bv2[ct] = bsum[pos];
#pragma unroll
            for (int kt = 0; kt < 4; kt++)
                wfr[ct][kt] = *(const short8*)(Wihp + (size_t)pos * 128 + kt * 32 + q * 8);
        }
#pragma unroll 1
        for (int rt = 0; rt < 4; rt++) {
            floatx4 a2[4];
#pragma unroll
            for (int ct = 0; ct < 4; ct++) a2[ct] = (floatx4)(0.f);
#pragma unroll
            for (int kt = 0; kt < 4; kt++) {
                short8 af = *(const short8*)&T[rt * 16 + lid][kt * 32 + q * 8];
#pragma unroll
                for (int ct = 0; ct < 4; ct++)
                    a2[ct] = __builtin_amdgcn_mfma_f32_16x16x32_bf16(af, wfr[ct][kt], a2[ct], 0, 0, 0);
            }
#pragma unroll
            for (int r = 0; r < 4; r++) {
                int row = rowbase + rt * 16 + q * 4 + r;
                if (row < N) {
                    short4v ov;
#pragma unroll
                    for (int ct = 0; ct < 4; ct++)
                        ov[ct] = f2bfs(a2[ct][r] + bv2[ct]);
                    *(short4v*)(Yout + (size_t)row * 512 + w * 128 + lid * 8 + hf * 4) = ov;
                }
            }
        }
    }
}

// ---------------------------------------------------------------------------
// Fused between-layers: h1 = relu(aggr@Wl^T+bl+X@Wr^T); xp2 = relu(h1@Wp2^T+bp2);
// Y2 via pre-permuted Wihp2/bsum2. X read RAW (inline cvt). (256,3).
// ---------------------------------------------------------------------------
__global__ __launch_bounds__(256, 3) void fused_lin_xp_y(
    const bf16* __restrict__ aggr, const bf16* __restrict__ Wl, const bf16* __restrict__ bl,
    const void* __restrict__ Xraw, const int* __restrict__ flag,
    const bf16* __restrict__ Wr,
    bf16* __restrict__ h1out,
    const bf16* __restrict__ Wp2, const bf16* __restrict__ bp2,
    const bf16* __restrict__ Wihp2, const float* __restrict__ bsum2,
    bf16* __restrict__ Yout, int N)
{
    __shared__ bf16 T1[64][136];
    __shared__ bf16 T2[64][136];
    const int tid = threadIdx.x;
    const int w = tid >> 6, l = tid & 63, q = l >> 4, lid = l & 15;
    const int rowbase = blockIdx.x * 64;
    const bool isf32 = (*flag != 0);

    int arow = rowbase + w * 16 + lid;
    if (arow >= N) arow = N - 1;

    // ---- stage A: h1 = relu(aggr@Wl^T + bl + X@Wr^T), kt halves per GEMM ----
    {
        floatx4 acc[8];
        float bvv[8];
#pragma unroll
        for (int ct = 0; ct < 8; ct++) {
            acc[ct] = (floatx4)(0.f);
            bvv[ct] = bf2f(bl[lid * 8 + ct]);
        }
#pragma unroll
        for (int kh = 0; kh < 2; kh++) {
            short8 bfrag[8][2];
#pragma unroll
            for (int ct = 0; ct < 8; ct++)
#pragma unroll
                for (int k2 = 0; k2 < 2; k2++)
                    bfrag[ct][k2] = *(const short8*)(Wl + (size_t)(lid * 8 + ct) * 128 + (kh * 2 + k2) * 32 + q * 8);
#pragma unroll
            for (int k2 = 0; k2 < 2; k2++) {
                short8 af = *(const short8*)(aggr + (size_t)arow * 128 + (kh * 2 + k2) * 32 + q * 8);
#pragma unroll
                for (int ct = 0; ct < 8; ct++)
                    acc[ct] = __builtin_amdgcn_mfma_f32_16x16x32_bf16(af, bfrag[ct][k2], acc[ct], 0, 0, 0);
            }
        }
#pragma unroll
        for (int kh = 0; kh < 2; kh++) {
            short8 bfrag[8][2];
#pragma unroll
            for (int ct = 0; ct < 8; ct++)
#pragma unroll
                for (int k2 = 0; k2 < 2; k2++)
                    bfrag[ct][k2] = *(const short8*)(Wr + (size_t)(lid * 8 + ct) * 128 + (kh * 2 + k2) * 32 + q * 8);
#pragma unroll
            for (int k2 = 0; k2 < 2; k2++) {
                short8 af = load_x8(Xraw, isf32, (size_t)arow, (kh * 2 + k2) * 32 + q * 8);
#pragma unroll
                for (int ct = 0; ct < 8; ct++)
                    acc[ct] = __builtin_amdgcn_mfma_f32_16x16x32_bf16(af, bfrag[ct][k2], acc[ct], 0, 0, 0);
            }
        }
#pragma unroll
        for (int r = 0; r < 4; r++) {
            short8 ov;
#pragma unroll
            for (int ct = 0; ct < 8; ct++)
                ov[ct] = f2bfs(fmaxf(acc[ct][r] + bvv[ct], 0.f));
            int rl = w * 16 + q * 4 + r;
            *(short8*)&T1[rl][lid * 8] = ov;
            int row = rowbase + rl;
            if (row < N) *(short8*)(h1out + (size_t)row * 128 + lid * 8) = ov;
        }
    }
    __syncthreads();

    // ---- stage B: xp2 = relu(h1@Wp2^T + bp2) -> T2, kt halves ----
    {
        floatx4 acc[8];
        float bvv[8];
#pragma unroll
        for (int ct = 0; ct < 8; ct++) {
            acc[ct] = (floatx4)(0.f);
            bvv[ct] = bf2f(bp2[lid * 8 + ct]);
        }
#pragma unroll
        for (int kh = 0; kh < 2; kh++) {
            short8 bfrag[8][2];
#pragma unroll
            for (int ct = 0; ct < 8; ct++)
#pragma unroll
                for (int k2 = 0; k2 < 2; k2++)
                    bfrag[ct][k2] = *(const short8*)(Wp2 + (size_t)(lid * 8 + ct) * 128 + (kh * 2 + k2) * 32 + q * 8);
#pragma unroll
            for (int k2 = 0; k2 < 2; k2++) {
                short8 af = *(const short8*)&T1[w * 16 + lid][(kh * 2 + k2) * 32 + q * 8];
#pragma unroll
                for (int ct = 0; ct < 8; ct++)
                    acc[ct] = __builtin_amdgcn_mfma_f32_16x16x32_bf16(af, bfrag[ct][k2], acc[ct], 0, 0, 0);
            }
        }
#pragma unroll
        for (int r = 0; r < 4; r++) {
            short8 ov;
#pragma unroll
            for (int ct = 0; ct < 8; ct++)
                ov[ct] = f2bfs(fmaxf(acc[ct][r] + bvv[ct], 0.f));
            *(short8*)&T2[w * 16 + q * 4 + r][lid * 8] = ov;
        }
    }
    __syncthreads();

    // ---- stage C: Y2 chunks; wave w = chunk w; ct halves; 4 rowtiles ----
#pragma unroll 1
    for (int hf = 0; hf < 2; hf++) {
        short8 wfr[4][4];
        float bv2[4];
#pragma unroll
        for (int ct = 0; ct < 4; ct++) {
            int pos = w * 128 + lid * 8 + hf * 4 + ct;
            bv2[ct] = bsum2[pos];
#pragma unroll
            for (int kt = 0; kt < 4; kt++)
                wfr[ct][kt] = *(const short8*)(Wihp2 + (size_t)pos * 128 + kt * 32 + q * 8);
        }
#pragma unroll 1
        for (int rt = 0; rt < 4; rt++) {
            floatx4 a2[4];
#pragma unroll
            for (int ct = 0; ct < 4; ct++) a2[ct] = (floatx4)(0.f);
#pragma unroll
            for (int kt = 0; kt < 4; kt++) {
                short8 af = *(const short8*)&T2[rt * 16 + lid][kt * 32 + q * 8];
#pragma unroll
                for (int ct = 0; ct < 4; ct++)
                    a2[ct] = __builtin_amdgcn_mfma_f32_16x16x32_bf16(af, wfr[ct][kt], a2[ct], 0, 0, 0);
            }
#pragma unroll
            for (int r = 0; r < 4; r++) {
                int row = rowbase + rt * 16 + q * 4 + r;
                if (row < N) {
                    short4v ov;
#pragma unroll
                    for (int ct = 0; ct < 4; ct++)
                        ov[ct] = f2bfs(a2[ct][r] + bv2[ct]);
                    *(short4v*)(Yout + (size_t)row * 512 + w * 128 + lid * 8 + hf * 4) = ov;
                }
            }
        }
    }
}

// ---------------------------------------------------------------------------
// LSTM neighbor aggregation (r14/r17 plateau core).
// EPI=0: final h -> aggr. EPI=1: h stays in hb; h1 rows DMA'd (SWIZZLED src,
// linear LDS dest) into dead stage[0] during t=15; epilogue (waves 0-2)
// computes out = h@Wl2^T+bl2+h1@Wr2^T with XOR read (no bank conflicts).
// ---------------------------------------------------------------------------
template <int EPI>
__global__ __launch_bounds__(512, 4) void lstm_aggr(
    const bf16* __restrict__ Y,     // [N,512] PERMUTED, prescaled pre-activations
    const int* __restrict__ esrc,   // [N,16]
    const bf16* __restrict__ Whh,   // [512,128] prescaled by gate
    bf16* __restrict__ aggr,        // [N,128] out: final h (EPI=0)
    int N,
    const bf16* __restrict__ Wl2, const bf16* __restrict__ bl2,
    const bf16* __restrict__ Wr2, const bf16* __restrict__ h1,
    void* __restrict__ outp, const int* __restrict__ oflag)
{
    __shared__ alignas(16) short stage[2][8][1024];  // [buf][wave][2KB slice]
    __shared__ alignas(16) bf16 hb[2][16][136];
    __shared__ int srcl[16][16];    // [t][node]

    const int tid = threadIdx.x;
    const int w = tid >> 6, l = tid & 63, q = l >> 4, lid = l & 15;
    const int nodebase = blockIdx.x * 16;   // N = 50000 = 3125*16, exact

    if (tid < 256) {
        int node = tid >> 4, t = tid & 15;
        srcl[t][node] = esrc[(size_t)(nodebase + node) * 16 + t];
    }

    // Whh A-fragments: wf[g][kt]; A-row = gatecol = g*128 + 16*w + lid
    short8 wf[4][4];
#pragma unroll
    for (int g = 0; g < 4; g++) {
        int gc = g * 128 + 16 * w + lid;
#pragma unroll
        for (int kt = 0; kt < 4; kt++)
            wf[g][kt] = *(const short8*)(Whh + (size_t)gc * 128 + kt * 32 + q * 8);
    }

    float c[4];
#pragma unroll
    for (int r = 0; r < 4; r++) c[r] = 0.f;

    const int laneoff = w * 64 + q * 8;

    __syncthreads();   // srcl visible before first DMA

    // prologue: pairs 0,1 -> bufs 0,1 (oldest-first)
    {
        int s0 = srcl[0][lid];
        dma2(Y + (size_t)s0 * 512 + laneoff, &stage[0][w][0], &stage[0][w][512]);
        int s1 = srcl[1][lid];
        dma2(Y + (size_t)s1 * 512 + laneoff, &stage[1][w][0], &stage[1][w][512]);
    }

#pragma unroll 2
    for (int t = 0; t < 16; t++) {
        const int cb = t & 1;

        if (t == 15) asm volatile("s_waitcnt vmcnt(0)" ::: "memory");
        else         asm volatile("s_waitcnt vmcnt(2)" ::: "memory");

        // EPI=1: stage[0] dead at t=15 (pair-14 retired): DMA the block's 16 h1
        // rows, rule-21 pre-swizzle (lane chunk lid^(row&7); linear LDS dest).
        if (EPI == 1 && t == 15 && w < 4) {
            int row = w * 4 + q;
            const bf16* gp = h1 + (size_t)(nodebase + row) * 128 + (lid ^ (row & 7)) * 8;
            dma1(gp, (char*)&stage[0][0][0] + w * 1024);
        }

        int snext = (t < 14) ? srcl[t + 2][lid] : 0;

        floatx4 acc[4];
        {
            const short* wbuf = &stage[cb][w][0];
            short8 y0 = *(const short8*)&wbuf[q * 256 + lid * 8];
            short8 y1 = *(const short8*)&wbuf[q * 256 + 128 + lid * 8];
#pragma unroll
            for (int g = 0; g < 2; g++)
#pragma unroll
                for (int r = 0; r < 4; r++) {
                    acc[g][r]     = bfs2f(y0[g * 4 + r]);
                    acc[2 + g][r] = bfs2f(y1[g * 4 + r]);
                }
        }

        if (t) {   // h0 = 0: skip recurrent MFMA at t=0
#pragma unroll
            for (int kt = 0; kt < 4; kt++) {
                short8 bh = *(const short8*)&hb[cb][lid][kt * 32 + q * 8];
#pragma unroll
                for (int g = 0; g < 4; g++)
                    acc[g] = __builtin_amdgcn_mfma_f32_16x16x32_bf16(wf[g][kt], bh, acc[g], 0, 0, 0);
            }
        }

        {
            short4v hv;
#pragma unroll
            for (int r = 0; r < 4; r++)
                hv[r] = f2bfs(cell(acc[0][r], acc[1][r], acc[2][r], acc[3][r], c[r]));
            if (t < 15) *(short4v*)&hb[cb ^ 1][lid][16 * w + 4 * q] = hv;
            else if (EPI == 0)
                *(short4v*)(aggr + (size_t)(nodebase + lid) * 128 + 16 * w + 4 * q) = hv;
            else
                *(short4v*)&hb[0][lid][16 * w + 4 * q] = hv;   // cb^1 at t=15
        }

        if (t < 15) {
            asm volatile("s_waitcnt lgkmcnt(0)" ::: "memory");
            if (t < 14)
                dma2(Y + (size_t)snext * 512 + laneoff, &stage[cb][w][0], &stage[cb][w][512]);
            __builtin_amdgcn_s_barrier();   // hb exchange only — no vmcnt drain
        }
    }

    if constexpr (EPI == 1) {
        asm volatile("s_waitcnt vmcnt(0)" ::: "memory");   // h1 rows landed
        short8 blf[4], brf[4];
        int j = w * 16 + lid;
        int jc = j < 40 ? j : 39;
        if (w < 3) {
#pragma unroll
            for (int kt = 0; kt < 4; kt++) {
                blf[kt] = *(const short8*)(Wl2 + (size_t)jc * 128 + kt * 32 + q * 8);
                brf[kt] = *(const short8*)(Wr2 + (size_t)jc * 128 + kt * 32 + q * 8);
            }
        }
        asm volatile("s_waitcnt lgkmcnt(0)" ::: "memory");
        __builtin_amdgcn_s_barrier();      // hb[0] + h1 stage complete
        if (w < 3) {                       // 3 col-tiles cover C=40
            const short* xs = &stage[0][0][0];
            floatx4 o = (floatx4)(0.f);
#pragma unroll
            for (int kt = 0; kt < 4; kt++) {
                short8 ah = *(const short8*)&hb[0][lid][kt * 32 + q * 8];
                o = __builtin_amdgcn_mfma_f32_16x16x32_bf16(ah, blf[kt], o, 0, 0, 0);
            }
#pragma unroll
            for (int kt = 0; kt < 4; kt++) {
                short8 a1 = *(const short8*)&xs[lid * 128 + (((kt * 4 + q) ^ (lid & 7)) << 3)];
                o = __builtin_amdgcn_mfma_f32_16x16x32_bf16(a1, brf[kt], o, 0, 0, 0);
            }
            float bv = bf2f(bl2[jc]);
            bool of32 = (*oflag != 0);
            if (j < 40) {
#pragma unroll
                for (int r = 0; r < 4; r++) {
                    int node = nodebase + q * 4 + r;
                    float v = o[r] + bv;
                    size_t idx = (size_t)node * 40 + j;
                    if (of32) ((float*)outp)[idx] = v;
                    else      ((bf16*)outp)[idx]  = f2bf(v);
                }
            }
        }
    }
}

extern "C" void kernel_launch(void* const* d_in, const int* in_sizes, int n_in,
                              void* d_out, int out_size, void* d_ws, size_t ws_size,
                              hipStream_t stream)
{
    const int N = 50000;
    const int* es = (const int*)d_in[1];
    char* ws = (char*)d_ws;

    struct Ent { int di; int di2; int mode; };
    Ent ents[16] = {
        {8,  -1, 0}, {9,  -1, 0},            // Wp1, bp1
        {10, -1, 2}, {11, -1, 1},            // Wihp1, Whh1
        {12, 13, 3},                         // bsum1 (f32)
        {14, -1, 0}, {15, -1, 0}, {16, -1, 0},  // Wl1, bl1, Wr1
        {17, -1, 0}, {18, -1, 0},            // Wp2, bp2
        {19, -1, 2}, {20, -1, 1},            // Wihp2, Whh2
        {21, 22, 3},                         // bsum2 (f32)
        {23, -1, 0}, {24, -1, 0}, {25, -1, 0},  // Wl2, bl2, Wr2
    };
    bf16* conv[16];
    size_t off = 0;
    CvtAll ca;
    for (int k = 0; k < 16; k++) {
        conv[k] = (bf16*)ws + off;
        int n = in_sizes[ents[k].di];
        ca.t[k].src  = d_in[ents[k].di];
        ca.t[k].src2 = ents[k].di2 >= 0 ? d_in[ents[k].di2] : nullptr;
        ca.t[k].dst  = conv[k];
        ca.t[k].n    = n;
        ca.t[k].mode = ents[k].mode;
        size_t elems = (ents[k].mode == 3) ? (size_t)n * 2 : (size_t)n;  // f32 dst
        off += (elems + 63) & ~(size_t)63;
    }
    int* flag  = (int*)(ws + ((size_t)15 << 20));
    bf16* aggr = (bf16*)(ws + ((size_t)16 << 20));   // [N,128] (layer-1 only)
    bf16* Y    = (bf16*)(ws + ((size_t)30 << 20));   // [N,512] permuted
    bf16* h1   = (bf16*)(ws + ((size_t)84 << 20));   // [N,128]

    const void* xraw = d_in[0];
    const bf16 *Wp1  = conv[0],  *bp1 = conv[1];
    const bf16 *Wihp1 = conv[2], *Whh1 = conv[3];
    const float *bsum1 = (const float*)conv[4];
    const bf16 *Wl1 = conv[5], *bl1 = conv[6], *Wr1 = conv[7];
    const bf16 *Wp2 = conv[8], *bp2 = conv[9];
    const bf16 *Wihp2 = conv[10], *Whh2 = conv[11];
    const float *bsum2 = (const float*)conv[12];
    const bf16 *Wl2 = conv[13], *bl2 = conv[14], *Wr2 = conv[15];

    dim3 blk(256);
    const int gx = (N + 63) / 64;    // 782
    const int gl = N / 16;           // 3125 (exact)

    convert_inputs<<<dim3(128), blk, 0, stream>>>(
        ca, (const unsigned short*)d_in[0], flag);

    // ---- layer 1 ----
    fused_xp_y<<<dim3(gx), blk, 0, stream>>>(xraw, flag, Wp1, bp1, Wihp1, bsum1, Y, N);
    lstm_aggr<0><<<dim3(gl), dim3(512), 0, stream>>>(
        Y, es, Whh1, aggr, N, nullptr, nullptr, nullptr, nullptr, nullptr, nullptr);

    // ---- between layers: lin1 -> xp2 -> Y2 ----
    fused_lin_xp_y<<<dim3(gx), blk, 0, stream>>>(
        aggr, Wl1, bl1, xraw, flag, Wr1, h1, Wp2, bp2, Wihp2, bsum2, Y, N);

    // ---- lstm2 + fused final linear ----
    lstm_aggr<1><<<dim3(gl), dim3(512), 0, stream>>>(
        Y, es, Whh2, nullptr, N, Wl2, bl2, Wr2, h1, d_out, flag);
}

// Round 13
// 575.455 us; speedup vs baseline: 1.0067x; 1.0067x over previous
//
#include <hip/hip_runtime.h>
#include <hip/hip_bf16.h>

// GCN_5016521802361: 2x SAGEConv(aggr='lstm', project=True), N=50000, D=16, F=128, C=40.
// Round 26: r25 2-group lstm (32 nodes/block, one barrier/step, shared wf,
// 3 rotating stage buffers) with the h1-staging bug FIXED:
//  - h1 DMA dest is BYTE-based w*1024 into stage[2] (4 rows x 256B per wave,
//    contiguous rr*256 layout the epilogue reads). r25 used &stage[2][w][0]
//    (2048B stride) -> rows 4..31 landed wrong -> absmax 7.9.
//  - hvA/hvB stored immediately after each group's cells (shorter live ranges,
//    fits the 128-reg cap at launch_bounds(512,4)).
//  - t-loop fully unrolled: period-3 rotation constants fold to immediates.
// Producers/convert r24-exact.

typedef __hip_bfloat16 bf16;
typedef __attribute__((ext_vector_type(8))) short short8;
typedef __attribute__((ext_vector_type(4))) short short4v;
typedef __attribute__((ext_vector_type(4))) float floatx4;
typedef __attribute__((ext_vector_type(4))) float float4v;

#define LOG2E 1.4426950408889634f
#define TWOL  2.8853900817779268f

__device__ __forceinline__ float bf2f(bf16 v) { return __bfloat162float(v); }
__device__ __forceinline__ bf16  f2bf(float v) { return __float2bfloat16(v); }
__device__ __forceinline__ float bfs2f(short s) {
    union { float f; unsigned u; } v; v.u = ((unsigned)(unsigned short)s) << 16; return v.f;
}
__device__ __forceinline__ short f2bfs(float v) {
    bf16 b = __float2bfloat16(v); return *(short*)&b;
}

__device__ __forceinline__ float ex2(float x) {
#if __has_builtin(__builtin_amdgcn_exp2f)
    return __builtin_amdgcn_exp2f(x);
#else
    return exp2f(x);
#endif
}

// LSTM cell, prescaled inputs: i_,f_,o_ carry log2e, g_ carries 2*log2e,
// c is tracked as (2*log2e)*c_true. Single merged rcp on the c path.
__device__ __forceinline__ float cell(float i_, float f_, float g_, float o_, float& c) {
    float ei = ex2(-i_), ef = ex2(-f_), eg = ex2(g_), eo = ex2(-o_);
    float A = (1.f + ei) * (eg + 1.f);
    float B = 1.f + ef;
    float cn = fmaf(c, A, fmaf(eg, TWOL, -TWOL) * B) * __builtin_amdgcn_rcpf(A * B);
    c = cn;
    float ec = ex2(cn);
    return (ec - 1.f) * __builtin_amdgcn_rcpf((ec + 1.f) * (1.f + eo));
}

// Permuted-Y memory position p -> source gate row. Convert-time only.
__device__ __forceinline__ int ydecode(int p) {
    int pw = (p >> 6) & 7, pq = (p >> 4) & 3, pg = (p >> 2) & 3, pr = p & 3;
    return pg * 128 + pw * 16 + pq * 4 + pr;
}

// load 8 bf16 of row `row` at element offset `off` from raw x (f32 or bf16)
__device__ __forceinline__ short8 load_x8(const void* X, bool isf32, size_t row, int off) {
    if (isf32) {
        const float* p = (const float*)X + row * 128 + off;
        float4v a = *(const float4v*)p, b = *(const float4v*)(p + 4);
        short8 r;
#pragma unroll
        for (int j = 0; j < 4; j++) { r[j] = f2bfs(a[j]); r[4 + j] = f2bfs(b[j]); }
        return r;
    }
    return *(const short8*)((const bf16*)X + row * 128 + off);
}

__device__ __forceinline__ void dma1(const bf16* gp, void* lp) {
    __builtin_amdgcn_global_load_lds(
        (const __attribute__((address_space(1))) void*)gp,
        (__attribute__((address_space(3))) void*)lp, 16, 0, 0);
}

__device__ __forceinline__ void dma2(const bf16* gp, void* lp0, void* lp1) {
    dma1(gp, lp0);
    dma1(gp + 32, lp1);
}

// mode 0: plain copy; mode 1: Whh gate-scale; mode 2: Wih permute+scale;
// mode 3: bias pair sum -> f32 dst (permuted+scaled)
struct Cvt { const void* src; const void* src2; bf16* dst; int n; int mode; };
struct CvtAll { Cvt t[16]; };

__global__ void convert_inputs(CvtAll ca, const unsigned short* __restrict__ xb,
                               int* __restrict__ flag) {
    __shared__ int sflag;
    {
        int cnt = 0;
        for (int i = threadIdx.x; i < 1024; i += blockDim.x) {
            int e = (xb[i] >> 7) & 0xFF;
            cnt += (e >= 0xC8);
        }
        if (threadIdx.x == 0) sflag = 0;
        __syncthreads();
        if (cnt) atomicAdd(&sflag, cnt);
        __syncthreads();
    }
    const bool isf32 = (sflag >= 16);
    if (blockIdx.x == 0 && threadIdx.x == 0) *flag = isf32 ? 1 : 0;

    const int stride = gridDim.x * blockDim.x;
    const int tid0 = blockIdx.x * blockDim.x + threadIdx.x;
#pragma unroll 1
    for (int k = 0; k < 16; k++) {
        const int n = ca.t[k].n, mode = ca.t[k].mode;
        if (mode == 3) {
            const float* a32 = (const float*)ca.t[k].src;
            const float* b32 = (const float*)ca.t[k].src2;
            const short* a16 = (const short*)ca.t[k].src;
            const short* b16 = (const short*)ca.t[k].src2;
            float* df = (float*)ca.t[k].dst;
            for (int i = tid0; i < n; i += stride) {
                int yd = ydecode(i);
                float va = isf32 ? a32[yd] : bfs2f(a16[yd]);
                float vb = isf32 ? b32[yd] : bfs2f(b16[yd]);
                float m = ((((unsigned)i >> 2) & 3) == 2) ? TWOL : LOG2E;
                df[i] = (va + vb) * m;
            }
            continue;
        }
        const int n8 = n >> 3;
        bf16* d = ca.t[k].dst;
        for (int i = tid0; i < n8; i += stride) {
            int si = i;
            float m = 1.f;
            bool scaled = false;
            if (mode == 1) {
                m = ((((unsigned)i >> 11) & 3) == 2) ? TWOL : LOG2E; scaled = true;
            } else if (mode == 2) {
                int row = i >> 4;
                si = ydecode(row) * 16 + (i & 15);
                m = ((((unsigned)row >> 2) & 3) == 2) ? TWOL : LOG2E; scaled = true;
            }
            short8 ov;
            if (isf32) {
                const float4v* sp = (const float4v*)ca.t[k].src;
                float4v a = sp[2 * si], b = sp[2 * si + 1];
#pragma unroll
                for (int j = 0; j < 4; j++) {
                    ov[j]     = f2bfs(a[j] * m);
                    ov[4 + j] = f2bfs(b[j] * m);
                }
            } else {
                short8 sv = ((const short8*)ca.t[k].src)[si];
                if (scaled) {
#pragma unroll
                    for (int j = 0; j < 8; j++) ov[j] = f2bfs(bfs2f(sv[j]) * m);
                } else ov = sv;
            }
            ((short8*)d)[i] = ov;
        }
        if (mode == 0)
            for (int i = (n8 << 3) + tid0; i < n; i += stride) {
                float v = isf32 ? ((const float*)ca.t[k].src)[i]
                                : bfs2f(((const short*)ca.t[k].src)[i]);
                d[i] = f2bf(v);
            }
    }
}

// ---------------------------------------------------------------------------
// Fused layer entry: Y = (relu(X@Wp^T+bp)) @ Wihp^T(+bsum), permuted layout.
// ---------------------------------------------------------------------------
__global__ __launch_bounds__(256, 3) void fused_xp_y(
    const void* __restrict__ Xraw, const int* __restrict__ flag,
    const bf16* __restrict__ Wp, const bf16* __restrict__ bp,
    const bf16* __restrict__ Wihp, const float* __restrict__ bsum,
    bf16* __restrict__ Yout, int N)
{
    __shared__ bf16 T[64][136];
    const int tid = threadIdx.x;
    const int w = tid >> 6, l = tid & 63, q = l >> 4, lid = l & 15;
    const int rowbase = blockIdx.x * 64;
    const bool isf32 = (*flag != 0);

    int arow = rowbase + w * 16 + lid;
    if (arow >= N) arow = N - 1;

    // ---- stage A: xp = relu(X@Wp^T + bp) -> T (cols lid*8+ct), kt halves ----
    {
        floatx4 acc[8];
        float bvv[8];
#pragma unroll
        for (int ct = 0; ct < 8; ct++) {
            acc[ct] = (floatx4)(0.f);
            bvv[ct] = bf2f(bp[lid * 8 + ct]);
        }
#pragma unroll
        for (int kh = 0; kh < 2; kh++) {
            short8 bfrag[8][2];
#pragma unroll
            for (int ct = 0; ct < 8; ct++)
#pragma unroll
                for (int k2 = 0; k2 < 2; k2++)
                    bfrag[ct][k2] = *(const short8*)(Wp + (size_t)(lid * 8 + ct) * 128 + (kh * 2 + k2) * 32 + q * 8);
#pragma unroll
            for (int k2 = 0; k2 < 2; k2++) {
                short8 af = load_x8(Xraw, isf32, (size_t)arow, (kh * 2 + k2) * 32 + q * 8);
#pragma unroll
                for (int ct = 0; ct < 8; ct++)
                    acc[ct] = __builtin_amdgcn_mfma_f32_16x16x32_bf16(af, bfrag[ct][k2], acc[ct], 0, 0, 0);
            }
        }
#pragma unroll
        for (int r = 0; r < 4; r++) {
            short8 ov;
#pragma unroll
            for (int ct = 0; ct < 8; ct++)
                ov[ct] = f2bfs(fmaxf(acc[ct][r] + bvv[ct], 0.f));
            *(short8*)&T[w * 16 + q * 4 + r][lid * 8] = ov;
        }
    }
    __syncthreads();

    // ---- stage B: wave w = col chunk w; ct halves; 4 rowtiles each ----
#pragma unroll 1
    for (int hf = 0; hf < 2; hf++) {
        short8 wfr[4][4];
        float bv2[4];
#pragma unroll
        for (int ct = 0; ct < 4; ct++) {
            int pos = w * 128 + lid * 8 + hf * 4 + ct;
            bv2[ct] = bsum[pos];
#pragma unroll
            for (int kt = 0; kt < 4; kt++)
                wfr[ct][kt] = *(const short8*)(Wihp + (size_t)pos * 128 + kt * 32 + q * 8);
        }
#pragma unroll 1
        for (int rt = 0; rt < 4; rt++) {
            floatx4 a2[4];
#pragma unroll
            for (int ct = 0; ct < 4; ct++) a2[ct] = (floatx4)(0.f);
#pragma unroll
            for (int kt = 0; kt < 4; kt++) {
                short8 af = *(const short8*)&T[rt * 16 + lid][kt * 32 + q * 8];
#pragma unroll
                for (int ct = 0; ct < 4; ct++)
                    a2[ct] = __builtin_amdgcn_mfma_f32_16x16x32_bf16(af, wfr[ct][kt], a2[ct], 0, 0, 0);
            }
#pragma unroll
            for (int r = 0; r < 4; r++) {
                int row = rowbase + rt * 16 + q * 4 + r;
                if (row < N) {
                    short4v ov;
#pragma unroll
                    for (int ct = 0; ct < 4; ct++)
                        ov[ct] = f2bfs(a2[ct][r] + bv2[ct]);
                    *(short4v*)(Yout + (size_t)row * 512 + w * 128 + lid * 8 + hf * 4) = ov;
                }
            }
        }
    }
}

// ---------------------------------------------------------------------------
// Fused between-layers: h1 = relu(aggr@Wl^T+bl+X@Wr^T); xp2 = relu(h1@Wp2^T+bp2);
// Y2 via pre-permuted Wihp2/bsum2. X read RAW (inline cvt). (256,3).
// ---------------------------------------------------------------------------
__global__ __launch_bounds__(256, 3) void fused_lin_xp_y(
    const bf16* __restrict__ aggr, const bf16* __restrict__ Wl, const bf16* __restrict__ bl,
    const void* __restrict__ Xraw, const int* __restrict__ flag,
    const bf16* __restrict__ Wr,
    bf16* __restrict__ h1out,
    const bf16* __restrict__ Wp2, const bf16* __restrict__ bp2,
    const bf16* __restrict__ Wihp2, const float* __restrict__ bsum2,
    bf16* __restrict__ Yout, int N)
{
    __shared__ bf16 T1[64][136];
    __shared__ bf16 T2[64][136];
    const int tid = threadIdx.x;
    const int w = tid >> 6, l = tid & 63, q = l >> 4, lid = l & 15;
    const int rowbase = blockIdx.x * 64;
    const bool isf32 = (*flag != 0);

    int arow = rowbase + w * 16 + lid;
    if (arow >= N) arow = N - 1;

    // ---- stage A: h1 = relu(aggr@Wl^T + bl + X@Wr^T), kt halves per GEMM ----
    {
        floatx4 acc[8];
        float bvv[8];
#pragma unroll
        for (int ct = 0; ct < 8; ct++) {
            acc[ct] = (floatx4)(0.f);
            bvv[ct] = bf2f(bl[lid * 8 + ct]);
        }
#pragma unroll
        for (int kh = 0; kh < 2; kh++) {
            short8 bfrag[8][2];
#pragma unroll
            for (int ct = 0; ct < 8; ct++)
#pragma unroll
                for (int k2 = 0; k2 < 2; k2++)
                    bfrag[ct][k2] = *(const short8*)(Wl + (size_t)(lid * 8 + ct) * 128 + (kh * 2 + k2) * 32 + q * 8);
#pragma unroll
            for (int k2 = 0; k2 < 2; k2++) {
                short8 af = *(const short8*)(aggr + (size_t)arow * 128 + (kh * 2 + k2) * 32 + q * 8);
#pragma unroll
                for (int ct = 0; ct < 8; ct++)
                    acc[ct] = __builtin_amdgcn_mfma_f32_16x16x32_bf16(af, bfrag[ct][k2], acc[ct], 0, 0, 0);
            }
        }
#pragma unroll
        for (int kh = 0; kh < 2; kh++) {
            short8 bfrag[8][2];
#pragma unroll
            for (int ct = 0; ct < 8; ct++)
#pragma unroll
                for (int k2 = 0; k2 < 2; k2++)
                    bfrag[ct][k2] = *(const short8*)(Wr + (size_t)(lid * 8 + ct) * 128 + (kh * 2 + k2) * 32 + q * 8);
#pragma unroll
            for (int k2 = 0; k2 < 2; k2++) {
                short8 af = load_x8(Xraw, isf32, (size_t)arow, (kh * 2 + k2) * 32 + q * 8);
#pragma unroll
                for (int ct = 0; ct < 8; ct++)
                    acc[ct] = __builtin_amdgcn_mfma_f32_16x16x32_bf16(af, bfrag[ct][k2], acc[ct], 0, 0, 0);
            }
        }
#pragma unroll
        for (int r = 0; r < 4; r++) {
            short8 ov;
#pragma unroll
            for (int ct = 0; ct < 8; ct++)
                ov[ct] = f2bfs(fmaxf(acc[ct][r] + bvv[ct], 0.f));
            int rl = w * 16 + q * 4 + r;
            *(short8*)&T1[rl][lid * 8] = ov;
            int row = rowbase + rl;
            if (row < N) *(short8*)(h1out + (size_t)row * 128 + lid * 8) = ov;
        }
    }
    __syncthreads();

    // ---- stage B: xp2 = relu(h1@Wp2^T + bp2) -> T2, kt halves ----
    {
        floatx4 acc[8];
        float bvv[8];
#pragma unroll
        for (int ct = 0; ct < 8; ct++) {
            acc[ct] = (floatx4)(0.f);
            bvv[ct] = bf2f(bp2[lid * 8 + ct]);
        }
#pragma unroll
        for (int kh = 0; kh < 2; kh++) {
            short8 bfrag[8][2];
#pragma unroll
            for (int ct = 0; ct < 8; ct++)
#pragma unroll
                for (int k2 = 0; k2 < 2; k2++)
                    bfrag[ct][k2] = *(const short8*)(Wp2 + (size_t)(lid * 8 + ct) * 128 + (kh * 2 + k2) * 32 + q * 8);
#pragma unroll
            for (int k2 = 0; k2 < 2; k2++) {
                short8 af = *(const short8*)&T1[w * 16 + lid][(kh * 2 + k2) * 32 + q * 8];
#pragma unroll
                for (int ct = 0; ct < 8; ct++)
                    acc[ct] = __builtin_amdgcn_mfma_f32_16x16x32_bf16(af, bfrag[ct][k2], acc[ct], 0, 0, 0);
            }
        }
#pragma unroll
        for (int r = 0; r < 4; r++) {
            short8 ov;
#pragma unroll
            for (int ct = 0; ct < 8; ct++)
                ov[ct] = f2bfs(fmaxf(acc[ct][r] + bvv[ct], 0.f));
            *(short8*)&T2[w * 16 + q * 4 + r][lid * 8] = ov;
        }
    }
    __syncthreads();

    // ---- stage C: Y2 chunks; wave w = chunk w; ct halves; 4 rowtiles ----
#pragma unroll 1
    for (int hf = 0; hf < 2; hf++) {
        short8 wfr[4][4];
        float bv2[4];
#pragma unroll
        for (int ct = 0; ct < 4; ct++) {
            int pos = w * 128 + lid * 8 + hf * 4 + ct;
            bv2[ct] = bsum2[pos];
#pragma unroll
            for (int kt = 0; kt < 4; kt++)
                wfr[ct][kt] = *(const short8*)(Wihp2 + (size_t)pos * 128 + kt * 32 + q * 8);
        }
#pragma unroll 1
        for (int rt = 0; rt < 4; rt++) {
            floatx4 a2[4];
#pragma unroll
            for (int ct = 0; ct < 4; ct++) a2[ct] = (floatx4)(0.f);
#pragma unroll
            for (int kt = 0; kt < 4; kt++) {
                short8 af = *(const short8*)&T2[rt * 16 + lid][kt * 32 + q * 8];
#pragma unroll
                for (int ct = 0; ct < 4; ct++)
                    a2[ct] = __builtin_amdgcn_mfma_f32_16x16x32_bf16(af, wfr[ct][kt], a2[ct], 0, 0, 0);
            }
#pragma unroll
            for (int r = 0; r < 4; r++) {
                int row = rowbase + rt * 16 + q * 4 + r;
                if (row < N) {
                    short4v ov;
#pragma unroll
                    for (int ct = 0; ct < 4; ct++)
                        ov[ct] = f2bfs(a2[ct][r] + bv2[ct]);
                    *(short4v*)(Yout + (size_t)row * 512 + w * 128 + lid * 8 + hf * 4) = ov;
                }
            }
        }
    }
}

// ---------------------------------------------------------------------------
// LSTM neighbor aggregation, 2-group (32 nodes/block). One barrier per step
// covers both groups; wf shared; 3 rotating stage buffers (A 2-ahead, B
// 1-ahead). EPI=0: h -> aggr. EPI=1: h in hbA/hbB; 32 h1 rows staged into
// stage[2] (free at t=15; BYTE stride w*1024 => rows contiguous at rr*256B)
// with rule-21 swizzle; epilogue waves {0-2}=A, {4-6}=B compute
// out = h@Wl2^T+bl2+h1@Wr2^T.
// ---------------------------------------------------------------------------
template <int EPI>
__global__ __launch_bounds__(512, 4) void lstm_aggr(
    const bf16* __restrict__ Y,     // [N,512] PERMUTED, prescaled pre-activations
    const int* __restrict__ esrc,   // [N,16]
    const bf16* __restrict__ Whh,   // [512,128] prescaled by gate
    bf16* __restrict__ aggr,        // [N,128] out: final h (EPI=0)
    int N,
    const bf16* __restrict__ Wl2, const bf16* __restrict__ bl2,
    const bf16* __restrict__ Wr2, const bf16* __restrict__ h1,
    void* __restrict__ outp, const int* __restrict__ oflag)
{
    __shared__ alignas(16) short stage[3][8][1024];  // 48KB: 3 rotating buffers
    __shared__ alignas(16) bf16 hbA[2][16][136];
    __shared__ alignas(16) bf16 hbB[2][16][136];
    __shared__ int srcl[16][32];    // [t][node 0..31]

    const int tid = threadIdx.x;
    const int w = tid >> 6, l = tid & 63, q = l >> 4, lid = l & 15;
    const int nodebase = blockIdx.x * 32;
    const int nb2 = nodebase + 16;
    const bool hasB = nb2 < N;

    {
        int node = tid & 31, t = tid >> 5;   // 512 threads = [16][32] exactly
        int row = nodebase + node;
        if (row >= N) row = N - 1;
        srcl[t][node] = esrc[(size_t)row * 16 + t];
    }

    // Whh A-fragments (shared by both groups): A-row = g*128 + 16*w + lid
    short8 wf[4][4];
#pragma unroll
    for (int g = 0; g < 4; g++) {
        int gc = g * 128 + 16 * w + lid;
#pragma unroll
        for (int kt = 0; kt < 4; kt++)
            wf[g][kt] = *(const short8*)(Whh + (size_t)gc * 128 + kt * 32 + q * 8);
    }

    float cA[4], cB[4];
#pragma unroll
    for (int r = 0; r < 4; r++) { cA[r] = 0.f; cB[r] = 0.f; }

    short* const sbase = &stage[0][0][0];
    const int wb1k = w * 1024;
    int oA = wb1k;                 // buffer 0 slice
    int oB = 8192 + wb1k;          // buffer 1 slice
    const int K3 = 24576 + 3 * wb1k;   // oA+oB+oC invariant
    const int lo = w * 64 + q * 8;

    __syncthreads();   // srcl visible before first DMA

    // prologue: A0->buf0, B0->buf1, A1->buf2 (oldest-first; 6 outstanding)
    {
        dma2(Y + (size_t)srcl[0][lid] * 512 + lo,      sbase + oA, sbase + oA + 512);
        dma2(Y + (size_t)srcl[0][16 + lid] * 512 + lo, sbase + oB, sbase + oB + 512);
        int oC = K3 - oA - oB;
        dma2(Y + (size_t)srcl[1][lid] * 512 + lo,      sbase + oC, sbase + oC + 512);
    }

#pragma unroll
    for (int t = 0; t < 16; t++) {
        const int cb = t & 1;

        // ---- group A: wait, read, MFMA, cells, store ----
        if (t == 15) asm volatile("s_waitcnt vmcnt(2)" ::: "memory");
        else         asm volatile("s_waitcnt vmcnt(4)" ::: "memory");

        floatx4 acc[4];
        {
            const short* wbuf = sbase + oA;
            short8 y0 = *(const short8*)&wbuf[q * 256 + lid * 8];
            short8 y1 = *(const short8*)&wbuf[q * 256 + 128 + lid * 8];
#pragma unroll
            for (int g = 0; g < 2; g++)
#pragma unroll
                for (int r = 0; r < 4; r++) {
                    acc[g][r]     = bfs2f(y0[g * 4 + r]);
                    acc[2 + g][r] = bfs2f(y1[g * 4 + r]);
                }
        }
        if (t) {
#pragma unroll
            for (int kt = 0; kt < 4; kt++) {
                short8 bh = *(const short8*)&hbA[cb][lid][kt * 32 + q * 8];
#pragma unroll
                for (int g = 0; g < 4; g++)
                    acc[g] = __builtin_amdgcn_mfma_f32_16x16x32_bf16(wf[g][kt], bh, acc[g], 0, 0, 0);
            }
        }
        {
            short4v hvA;
#pragma unroll
            for (int r = 0; r < 4; r++)
                hvA[r] = f2bfs(cell(acc[0][r], acc[1][r], acc[2][r], acc[3][r], cA[r]));
            if (t < 15)        *(short4v*)&hbA[cb ^ 1][lid][16 * w + 4 * q] = hvA;
            else if (EPI == 0) *(short4v*)(aggr + (size_t)(nodebase + lid) * 128 + 16 * w + 4 * q) = hvA;
            else               *(short4v*)&hbA[0][lid][16 * w + 4 * q] = hvA;
        }

        // ---- group B: wait, read, MFMA, cells, store ----
        if (t == 15) asm volatile("s_waitcnt vmcnt(0)" ::: "memory");
        else         asm volatile("s_waitcnt vmcnt(2)" ::: "memory");

        // EPI=1: stage[2] is free at t=15 (rotation period 3, 15%3==0):
        // stage the block's 32 h1 rows. BYTE-based dest w*1024 (4 rows x 256B
        // per wave -> row rr at byte rr*256, matching the epilogue reads).
        if (EPI == 1 && t == 15) {
            int r = w * 4 + q;
            int node = nodebase + r;
            if (node >= N) node = N - 1;
            dma1(h1 + (size_t)node * 128 + (lid ^ (r & 7)) * 8,
                 (char*)&stage[2][0][0] + w * 1024);
        }

        {
            const short* wbuf = sbase + oB;
            short8 y0 = *(const short8*)&wbuf[q * 256 + lid * 8];
            short8 y1 = *(const short8*)&wbuf[q * 256 + 128 + lid * 8];
#pragma unroll
            for (int g = 0; g < 2; g++)
#pragma unroll
                for (int r = 0; r < 4; r++) {
                    acc[g][r]     = bfs2f(y0[g * 4 + r]);
                    acc[2 + g][r] = bfs2f(y1[g * 4 + r]);
                }
        }
        if (t) {
#pragma unroll
            for (int kt = 0; kt < 4; kt++) {
                short8 bh = *(const short8*)&hbB[cb][lid][kt * 32 + q * 8];
#pragma unroll
                for (int g = 0; g < 4; g++)
                    acc[g] = __builtin_amdgcn_mfma_f32_16x16x32_bf16(wf[g][kt], bh, acc[g], 0, 0, 0);
            }
        }
        {
            short4v hvB;
#pragma unroll
            for (int r = 0; r < 4; r++)
                hvB[r] = f2bfs(cell(acc[0][r], acc[1][r], acc[2][r], acc[3][r], cB[r]));
            if (t < 15)        *(short4v*)&hbB[cb ^ 1][lid][16 * w + 4 * q] = hvB;
            else if (EPI == 0) { if (hasB)
                *(short4v*)(aggr + (size_t)(nb2 + lid) * 128 + 16 * w + 4 * q) = hvB; }
            else               *(short4v*)&hbB[0][lid][16 * w + 4 * q] = hvB;
        }

        if (t < 15) {
            // stage reads + hb writes retired; freed buffers refill
            asm volatile("s_waitcnt lgkmcnt(0)" ::: "memory");
            dma2(Y + (size_t)srcl[t + 1][16 + lid] * 512 + lo,
                 sbase + oA, sbase + oA + 512);              // B(t+1)
            if (t < 14)
                dma2(Y + (size_t)srcl[t + 2][lid] * 512 + lo,
                     sbase + oB, sbase + oB + 512);          // A(t+2)
            __builtin_amdgcn_s_barrier();   // hb exchange only — no vmcnt drain
            // rotate (A,B,C) <- (C,A,B)  [constants after full unroll]
            int oC = K3 - oA - oB;
            oB = oA;
            oA = oC;
        }
    }

    if constexpr (EPI == 1) {
        asm volatile("s_waitcnt vmcnt(0)" ::: "memory");   // h1 rows landed
        const int grp = w >> 2;            // waves 0-2: group A; 4-6: group B
        const int we = w & 3;
        int j = we * 16 + lid;
        int jc = j < 40 ? j : 39;
        short8 blf[4], brf[4];
        if (we < 3) {
#pragma unroll
            for (int kt = 0; kt < 4; kt++) {
                blf[kt] = *(const short8*)(Wl2 + (size_t)jc * 128 + kt * 32 + q * 8);
                brf[kt] = *(const short8*)(Wr2 + (size_t)jc * 128 + kt * 32 + q * 8);
            }
        }
        asm volatile("s_waitcnt lgkmcnt(0)" ::: "memory");
        __builtin_amdgcn_s_barrier();      // hbA/hbB[0] + h1 stage complete
        if (we < 3 && (grp == 0 || hasB)) {
            const short* xs = &stage[2][0][0];
            const bf16 (*hbp)[136] = grp ? hbB[0] : hbA[0];
            const int rbase = grp * 16;
            floatx4 o = (floatx4)(0.f);
#pragma unroll
            for (int kt = 0; kt < 4; kt++) {
                short8 ah = *(const short8*)&hbp[lid][kt * 32 + q * 8];
                o = __builtin_amdgcn_mfma_f32_16x16x32_bf16(ah, blf[kt], o, 0, 0, 0);
            }
#pragma unroll
            for (int kt = 0; kt < 4; kt++) {
                short8 a1 = *(const short8*)&xs[(rbase + lid) * 128 + (((kt * 4 + q) ^ (lid & 7)) << 3)];
                o = __builtin_amdgcn_mfma_f32_16x16x32_bf16(a1, brf[kt], o, 0, 0, 0);
            }
            float bv = bf2f(bl2[jc]);
            bool of32 = (*oflag != 0);
            if (j < 40) {
#pragma unroll
                for (int r = 0; r < 4; r++) {
                    int node = nodebase + rbase + q * 4 + r;
                    float v = o[r] + bv;
                    size_t idx = (size_t)node * 40 + j;
                    if (of32) ((float*)outp)[idx] = v;
                    else      ((bf16*)outp)[idx]  = f2bf(v);
                }
            }
        }
    }
}

extern "C" void kernel_launch(void* const* d_in, const int* in_sizes, int n_in,
                              void* d_out, int out_size, void* d_ws, size_t ws_size,
                              hipStream_t stream)
{
    const int N = 50000;
    const int* es = (const int*)d_in[1];
    char* ws = (char*)d_ws;

    struct Ent { int di; int di2; int mode; };
    Ent ents[16] = {
        {8,  -1, 0}, {9,  -1, 0},            // Wp1, bp1
        {10, -1, 2}, {11, -1, 1},            // Wihp1, Whh1
        {12, 13, 3},                         // bsum1 (f32)
        {14, -1, 0}, {15, -1, 0}, {16, -1, 0},  // Wl1, bl1, Wr1
        {17, -1, 0}, {18, -1, 0},            // Wp2, bp2
        {19, -1, 2}, {20, -1, 1},            // Wihp2, Whh2
        {21, 22, 3},                         // bsum2 (f32)
        {23, -1, 0}, {24, -1, 0}, {25, -1, 0},  // Wl2, bl2, Wr2
    };
    bf16* conv[16];
    size_t off = 0;
    CvtAll ca;
    for (int k = 0; k < 16; k++) {
        conv[k] = (bf16*)ws + off;
        int n = in_sizes[ents[k].di];
        ca.t[k].src  = d_in[ents[k].di];
        ca.t[k].src2 = ents[k].di2 >= 0 ? d_in[ents[k].di2] : nullptr;
        ca.t[k].dst  = conv[k];
        ca.t[k].n    = n;
        ca.t[k].mode = ents[k].mode;
        size_t elems = (ents[k].mode == 3) ? (size_t)n * 2 : (size_t)n;  // f32 dst
        off += (elems + 63) & ~(size_t)63;
    }
    int* flag  = (int*)(ws + ((size_t)15 << 20));
    bf16* aggr = (bf16*)(ws + ((size_t)16 << 20));   // [N,128] (layer-1 only)
    bf16* Y    = (bf16*)(ws + ((size_t)30 << 20));   // [N,512] permuted
    bf16* h1   = (bf16*)(ws + ((size_t)84 << 20));   // [N,128]

    const void* xraw = d_in[0];
    const bf16 *Wp1  = conv[0],  *bp1 = conv[1];
    const bf16 *Wihp1 = conv[2], *Whh1 = conv[3];
    const float *bsum1 = (const float*)conv[4];
    const bf16 *Wl1 = conv[5], *bl1 = conv[6], *Wr1 = conv[7];
    const bf16 *Wp2 = conv[8], *bp2 = conv[9];
    const bf16 *Wihp2 = conv[10], *Whh2 = conv[11];
    const float *bsum2 = (const float*)conv[12];
    const bf16 *Wl2 = conv[13], *bl2 = conv[14], *Wr2 = conv[15];

    dim3 blk(256);
    const int gx = (N + 63) / 64;    // 782
    const int gl = (N + 31) / 32;    // 1563 (last block: A only)

    convert_inputs<<<dim3(128), blk, 0, stream>>>(
        ca, (const unsigned short*)d_in[0], flag);

    // ---- layer 1 ----
    fused_xp_y<<<dim3(gx), blk, 0, stream>>>(xraw, flag, Wp1, bp1, Wihp1, bsum1, Y, N);
    lstm_aggr<0><<<dim3(gl), dim3(512), 0, stream>>>(
        Y, es, Whh1, aggr, N, nullptr, nullptr, nullptr, nullptr, nullptr, nullptr);

    // ---- between layers: lin1 -> xp2 -> Y2 ----
    fused_lin_xp_y<<<dim3(gx), blk, 0, stream>>>(
        aggr, Wl1, bl1, xraw, flag, Wr1, h1, Wp2, bp2, Wihp2, bsum2, Y, N);

    // ---- lstm2 + fused final linear ----
    lstm_aggr<1><<<dim3(gl), dim3(512), 0, stream>>>(
        Y, es, Whh2, nullptr, N, Wl2, bl2, Wr2, h1, d_out, flag);
}